// Round 14
// baseline (194.428 us; speedup 1.0000x reference)
//
#include <hip/hip_runtime.h>
#include <hip/hip_bf16.h>

#define B_ 4
#define S_ 1024
#define D_ 2048
#define H_ 16
#define G_ 4
#define HD_ 128
#define NQKV_ 3072
#define SCALE_ 0.08838834764831845f
#define EPS_ 1e-6f

typedef __attribute__((ext_vector_type(8))) short bf16x8;
typedef __attribute__((ext_vector_type(4))) float f32x4;
typedef __attribute__((ext_vector_type(16))) float f32x16;

__device__ __forceinline__ float bf2f(unsigned short u){
  union { unsigned int i; float f; } v; v.i = ((unsigned int)u) << 16; return v.f;
}
__device__ __forceinline__ unsigned short f2bf(float f){
  union { float f; unsigned int i; } v; v.f = f;
  unsigned int x = v.i;
  return (unsigned short)((x + 0x7fffu + ((x >> 16) & 1u)) >> 16);
}
__device__ __forceinline__ void gld16(unsigned short* lds, const unsigned short* g){
  __builtin_amdgcn_global_load_lds(
      (const __attribute__((address_space(1))) unsigned int*)g,
      (__attribute__((address_space(3))) unsigned int*)lds, 16, 0, 0);
}

// ---------------- prep: x->bf16 (blocks 0..8191) + weight transposes ----------------
__global__ void prep(const float* __restrict__ x, const float* __restrict__ Wq,
                     const float* __restrict__ Wk, const float* __restrict__ Wv,
                     const float* __restrict__ Wo, unsigned short* __restrict__ xb,
                     unsigned short* __restrict__ wqkvT, unsigned short* __restrict__ woT){
  __shared__ float tile[64][65];
  const int bid = blockIdx.x;
  if (bid < 8192){
    int i = bid * 256 + threadIdx.x;
    const float4 v = ((const float4*)x)[i];
    ushort4 o;
    o.x = f2bf(v.x); o.y = f2bf(v.y); o.z = f2bf(v.z); o.w = f2bf(v.w);
    ((ushort4*)xb)[i] = o;
    return;
  }
  const int wb = bid - 8192;
  const float* src; unsigned short* dst; int N, rowoff, t, nx;
  if (wb < 1024){ src = Wq; dst = wqkvT; N = 2048; rowoff = 0;    t = wb;        nx = 32; }
  else if (wb < 1280){ src = Wk; dst = wqkvT; N = 512; rowoff = 2048; t = wb - 1024; nx = 8; }
  else if (wb < 1536){ src = Wv; dst = wqkvT; N = 512; rowoff = 2560; t = wb - 1280; nx = 8; }
  else { src = Wo; dst = woT; N = 2048; rowoff = 0; t = wb - 1536; nx = 32; }
  const int n0 = (t % nx) * 64, k0 = (t / nx) * 64;
  const int c = threadIdx.x & 63, rb = threadIdx.x >> 6;
  #pragma unroll
  for (int j = 0; j < 16; j++){
    int r = rb + j * 4;
    tile[r][c] = src[(size_t)(k0 + r) * N + n0 + c];
  }
  __syncthreads();
  const int c2 = threadIdx.x & 31, rb2 = threadIdx.x >> 5;
  #pragma unroll
  for (int j = 0; j < 8; j++){
    int r = rb2 + j * 8;
    unsigned int v = (unsigned int)f2bf(tile[2 * c2][r])
                   | ((unsigned int)f2bf(tile[2 * c2 + 1][r]) << 16);
    *(unsigned int*)&dst[(size_t)(n0 + r + rowoff) * 2048 + k0 + 2 * c2] = v;
  }
}

// ---------------- GEMM: C[M][N] = A[M][K] @ Bt[N][K]^T + bias ----------------
// 128x128 tile, BK=64, DOUBLE-BUFFERED LDS, T3-minimum 2-phase schedule:
// STAGE(next) -> ds_read(cur)+MFMA -> one __syncthreads per K-step (the vmcnt
// drain lands AFTER the compute, hiding load latency). XOR-swizzled LDS,
// XCD-chunked 1-D grid. MODE 1: fused RMS/RoPE + V->vt. MODE 0: f32 + bias.
template<int MODE>
__global__ __launch_bounds__(256, 2) void gemm_bt(const unsigned short* __restrict__ A,
    const unsigned short* __restrict__ Bt,
    const float* __restrict__ b0, const float* __restrict__ b1, const float* __restrict__ b2,
    const float* __restrict__ qn, const float* __restrict__ kn,
    void* __restrict__ Cout, unsigned short* __restrict__ vtOut, int M, int N, int K){
  const int tid = threadIdx.x, wid = tid >> 6, lane = tid & 63;
  const int l15 = lane & 15, l4 = lane >> 4;
  const int nwg = (N >> 7) * (M >> 7);
  const int chunk = nwg >> 3;
  const int ord = (blockIdx.x & 7) * chunk + (blockIdx.x >> 3);
  const int bn = (ord >> 5) * 128;           // M>>7 == 32
  const int bm = (ord & 31) * 128;
  const int wr = wid >> 1, wc = wid & 1;
  __shared__ __align__(16) unsigned short As[2][128 * 64];
  __shared__ __align__(16) unsigned short Bs[2][128 * 64];

  const int srow = lane >> 3;
  const int sofs = ((lane & 7) * 8) ^ (srow << 3);
  const unsigned short* pa = A  + (size_t)(bm + wid * 32 + srow) * K + sofs;
  const unsigned short* pb = Bt + (size_t)(bn + wid * 32 + srow) * K + sofs;

  #define STAGE_G(BUF, KOFF)                                                        \
    do {                                                                            \
      _Pragma("unroll")                                                             \
      for (int i_ = 0; i_ < 4; i_++){                                               \
        gld16(As[BUF] + wid * 2048 + i_ * 512, pa + (size_t)(i_ * 8) * K + (KOFF)); \
        gld16(Bs[BUF] + wid * 2048 + i_ * 512, pb + (size_t)(i_ * 8) * K + (KOFF)); \
      }                                                                             \
    } while (0)

  f32x4 acc[4][4];
  #pragma unroll
  for (int m2 = 0; m2 < 4; m2++)
    #pragma unroll
    for (int n2 = 0; n2 < 4; n2++) acc[m2][n2] = (f32x4){0.f, 0.f, 0.f, 0.f};

  const int rswz = (l15 & 7) << 3;

  #define COMPUTE(BUF)                                                              \
    do {                                                                            \
      bf16x8 af[4][2], bfv[4][2];                                                   \
      _Pragma("unroll")                                                             \
      for (int m2 = 0; m2 < 4; m2++)                                                \
        _Pragma("unroll")                                                           \
        for (int ks = 0; ks < 2; ks++)                                              \
          af[m2][ks] = *(const bf16x8*)&As[BUF][(wr * 64 + m2 * 16 + l15) * 64 +    \
              ((ks * 32 + l4 * 8) ^ rswz)];                                         \
      _Pragma("unroll")                                                             \
      for (int n2 = 0; n2 < 4; n2++)                                                \
        _Pragma("unroll")                                                           \
        for (int ks = 0; ks < 2; ks++)                                              \
          bfv[n2][ks] = *(const bf16x8*)&Bs[BUF][(wc * 64 + n2 * 16 + l15) * 64 +   \
              ((ks * 32 + l4 * 8) ^ rswz)];                                         \
      _Pragma("unroll")                                                             \
      for (int ks = 0; ks < 2; ks++)                                                \
        _Pragma("unroll")                                                           \
        for (int m2 = 0; m2 < 4; m2++)                                              \
          _Pragma("unroll")                                                         \
          for (int n2 = 0; n2 < 4; n2++)                                            \
            acc[m2][n2] = __builtin_amdgcn_mfma_f32_16x16x32_bf16(                  \
                af[m2][ks], bfv[n2][ks], acc[m2][n2], 0, 0, 0);                     \
    } while (0)

  // prologue: tile 0 into buf0, drain
  STAGE_G(0, 0);
  __syncthreads();
  // 2-step unrolled pipeline: stage next-buf before compute, one barrier per step
  for (int k0 = 0; k0 < K; k0 += 128){
    STAGE_G(1, k0 + 64);
    COMPUTE(0);
    __syncthreads();
    if (k0 + 128 < K) STAGE_G(0, k0 + 128);
    COMPUTE(1);
    __syncthreads();
  }

  #pragma unroll
  for (int n2 = 0; n2 < 4; n2++){
    int col = bn + wc * 64 + n2 * 16 + l15;
    float bias;
    if (MODE == 1) bias = col < 2048 ? b0[col] : (col < 2560 ? b1[col - 2048] : b2[col - 2560]);
    else           bias = b0[col];
    #pragma unroll
    for (int m2 = 0; m2 < 4; m2++)
      #pragma unroll
      for (int r = 0; r < 4; r++) acc[m2][n2][r] += bias;
  }

  if (MODE == 1 && bn < 2560){
    // ---- fused RMSNorm + RoPE ----
    float* ssq = (float*)As;
    float part[4][4];
    #pragma unroll
    for (int m2 = 0; m2 < 4; m2++)
      #pragma unroll
      for (int r = 0; r < 4; r++){
        float p = 0.f;
        #pragma unroll
        for (int n2 = 0; n2 < 4; n2++) p += acc[m2][n2][r] * acc[m2][n2][r];
        #pragma unroll
        for (int off = 1; off < 16; off <<= 1) p += __shfl_xor(p, off);
        part[m2][r] = p;
      }
    if (l15 == 0){
      #pragma unroll
      for (int m2 = 0; m2 < 4; m2++)
        #pragma unroll
        for (int r = 0; r < 4; r++) ssq[wid * 64 + m2 * 16 + l4 * 4 + r] = part[m2][r];
    }
    __syncthreads();
    float rn[4][4];
    #pragma unroll
    for (int m2 = 0; m2 < 4; m2++)
      #pragma unroll
      for (int r = 0; r < 4; r++){
        int idx = m2 * 16 + l4 * 4 + r;
        float tot = ssq[wid * 64 + idx] + ssq[(wid ^ 1) * 64 + idx];
        rn[m2][r] = rsqrtf(tot * (1.0f / 128.0f) + EPS_);
      }
    const float* scv = (bn < 2048) ? qn : kn;
    const float sq = (bn < 2048) ? SCALE_ : 1.0f;
    float invf[4], scl[4];
    #pragma unroll
    for (int n2 = 0; n2 < 4; n2++){
      int ch = wc * 64 + n2 * 16 + l15;
      invf[n2] = exp2f((float)(ch >> 1) * -0.20762051f);
      scl[n2] = scv[ch] * sq;
    }
    const bool odd = (l15 & 1);
    unsigned short* outq = (unsigned short*)Cout;
    #pragma unroll
    for (int m2 = 0; m2 < 4; m2++)
      #pragma unroll
      for (int r = 0; r < 4; r++){
        int row = bm + wr * 64 + m2 * 16 + l4 * 4 + r;
        float sf = (float)(row & (S_ - 1));
        #pragma unroll
        for (int n2 = 0; n2 < 4; n2++){
          float v = acc[m2][n2][r] * rn[m2][r] * scl[n2];
          float vp = __shfl_xor(v, 1);
          float th = sf * invf[n2];
          float sn = __sinf(th), cs = __cosf(th);
          float outv = odd ? (vp * sn + v * cs) : (v * cs - vp * sn);
          int col = bn + wc * 64 + n2 * 16 + l15;
          outq[(size_t)row * N + col] = f2bf(outv);
        }
      }
  } else if (MODE == 1){
    // ---- V tile -> vt transpose (2-pass LDS) ----
    const int b = bm >> 10;
    const int s0 = bm & 1023;
    const int g = (bn - 2560) >> 7;
    unsigned short* vtp = vtOut + (size_t)(b * G_ + g) * HD_ * (size_t)S_;
    unsigned short* tr = (unsigned short*)As;
    #pragma unroll
    for (int dh = 0; dh < 2; dh++){
      __syncthreads();
      if (wc == dh){
        #pragma unroll
        for (int n2 = 0; n2 < 4; n2++){
          int dp = n2 * 16 + l15;
          int cs = (dp & 7) << 3;
          #pragma unroll
          for (int m2 = 0; m2 < 4; m2++)
            #pragma unroll
            for (int r = 0; r < 4; r++){
              int s = wr * 64 + m2 * 16 + l4 * 4 + r;
              tr[dp * 128 + (s ^ cs)] = f2bf(acc[m2][n2][r]);
            }
        }
      }
      __syncthreads();
      int dp = tid >> 2;
      int sb = (tid & 3) * 32;
      int cs = (dp & 7) << 3;
      #pragma unroll
      for (int jj = 0; jj < 4; jj++){
        bf16x8 vv = *(const bf16x8*)&tr[dp * 128 + ((sb + jj * 8) ^ cs)];
        *(bf16x8*)&vtp[(size_t)(dh * 64 + dp) * S_ + s0 + sb + jj * 8] = vv;
      }
    }
  } else {
    #pragma unroll
    for (int m2 = 0; m2 < 4; m2++)
      #pragma unroll
      for (int n2 = 0; n2 < 4; n2++){
        int col = bn + wc * 64 + n2 * 16 + l15;
        #pragma unroll
        for (int r = 0; r < 4; r++){
          int row = bm + wr * 64 + m2 * 16 + l4 * 4 + r;
          ((float*)Cout)[(size_t)row * N + col] = acc[m2][n2][r];
        }
      }
  }
  #undef STAGE_G
  #undef COMPUTE
}

// ---------------- flash attention: 32x32 MFMA, swapped QK^T, in-reg softmax ----
__global__ __launch_bounds__(256, 2) void attn(const unsigned short* __restrict__ qkv,
    const unsigned short* __restrict__ vt, unsigned short* __restrict__ outb){
  const int bid = blockIdx.x;
  const int xcd = bid & 7, idx = bid >> 3;
  const int gb = xcd * 2 + (idx & 1);
  const int qh = idx >> 1;
  const int qt = (qh < 16) ? (31 - qh) : (qh - 16);   // CU pair (qt, 31-qt): even work
  const int g = gb & 3, b = gb >> 2;
  const int tid = threadIdx.x, w = tid >> 6, lane = tid & 63;
  const int h = g * 4 + w;
  const int l31 = lane & 31, hi = lane >> 5;
  const int nkt = qt / 2 + 1;
  __shared__ __align__(16) unsigned short Ks[2][64 * 128];  // swz: col ^= (row&15)<<3
  __shared__ __align__(16) unsigned short Vs[2][128 * 64];  // swz: col ^= (row&7)<<3

  #define STAGE_KV(BF, KT)                                                              \
    do {                                                                                \
      _Pragma("unroll")                                                                 \
      for (int i_ = 0; i_ < 4; i_++){                                                   \
        int row_ = w * 16 + i_ * 4 + (lane >> 4);                                       \
        const unsigned short* src_ = qkv + (size_t)(b * S_ + (KT) * 64 + row_) * NQKV_  \
            + 2048 + g * HD_ + (((lane & 15) * 8) ^ ((row_ & 15) << 3));                \
        gld16(&Ks[BF][(w * 16 + i_ * 4) * 128], src_);                                  \
      }                                                                                 \
      _Pragma("unroll")                                                                 \
      for (int i_ = 0; i_ < 4; i_++){                                                   \
        int row_ = w * 32 + i_ * 8 + (lane >> 3);                                       \
        const unsigned short* src_ = vt + (size_t)((b * G_ + g) * HD_ + row_) * S_      \
            + (KT) * 64 + (((lane & 7) * 8) ^ ((row_ & 7) << 3));                       \
        gld16(&Vs[BF][(w * 32 + i_ * 8) * 64], src_);                                   \
      }                                                                                 \
    } while (0)

  bf16x8 qf[8];
  {
    const unsigned short* qp = qkv + ((size_t)b * S_ + qt * 32 + l31) * NQKV_ + h * HD_ + hi * 8;
    #pragma unroll
    for (int ks = 0; ks < 8; ks++) qf[ks] = *(const bf16x8*)&qp[ks * 16];
  }
  f32x16 o[4];
  #pragma unroll
  for (int d2 = 0; d2 < 4; d2++)
    #pragma unroll
    for (int r = 0; r < 16; r++) o[d2][r] = 0.f;
  float m_ = -1e30f, l_ = 0.f;

  int bf = 0;
  STAGE_KV(0, 0);
  __syncthreads();

  for (int kt = 0; kt < nkt; ++kt){
    if (kt + 1 < nkt){
      if (bf) STAGE_KV(0, kt + 1); else STAGE_KV(1, kt + 1);
    }
    const unsigned short* KB = Ks[bf];
    const unsigned short* VB = Vs[bf];
    const bool diag = (kt == nkt - 1);

    f32x16 sacc[2];
    #pragma unroll
    for (int kb = 0; kb < 2; kb++){
      f32x16 acc;
      #pragma unroll
      for (int r = 0; r < 16; r++) acc[r] = 0.f;
      __builtin_amdgcn_s_setprio(1);
      #pragma unroll
      for (int ks = 0; ks < 8; ks++){
        bf16x8 kf = *(const bf16x8*)&KB[(kb * 32 + l31) * 128 + ((ks * 16 + hi * 8) ^ ((l31 & 15) << 3))];
        acc = __builtin_amdgcn_mfma_f32_32x32x16_bf16(kf, qf[ks], acc, 0, 0, 0);
      }
      __builtin_amdgcn_s_setprio(0);
      sacc[kb] = acc;
    }

    if (diag){
      const int qrow = qt * 32 + l31;
      #pragma unroll
      for (int kb = 0; kb < 2; kb++)
        #pragma unroll
        for (int r = 0; r < 16; r++){
          int key = kt * 64 + kb * 32 + (r & 3) + 8 * (r >> 2) + 4 * hi;
          float v = sacc[kb][r] * SCALE_;
          sacc[kb][r] = (key > qrow) ? -1e30f : v;
        }
    } else {
      #pragma unroll
      for (int kb = 0; kb < 2; kb++)
        #pragma unroll
        for (int r = 0; r < 16; r++) sacc[kb][r] *= SCALE_;
    }

    float tm = sacc[0][0];
    #pragma unroll
    for (int r = 1; r < 16; r++) tm = fmaxf(tm, sacc[0][r]);
    #pragma unroll
    for (int r = 0; r < 16; r++) tm = fmaxf(tm, sacc[1][r]);
    tm = fmaxf(tm, __shfl_xor(tm, 32));

    float al = 1.0f;
    bool rescale = false;
    if (!__all(tm <= m_ + 8.0f)){
      float mn = fmaxf(m_, tm);
      al = __expf(m_ - mn);
      m_ = mn;
      rescale = true;
    }

    float rs = 0.f;
    #pragma unroll
    for (int kb = 0; kb < 2; kb++)
      #pragma unroll
      for (int r = 0; r < 16; r++){
        float p = __expf(sacc[kb][r] - m_);
        sacc[kb][r] = p;
        rs += p;
      }
    rs += __shfl_xor(rs, 32);
    l_ = l_ * al + rs;

    if (rescale){
      #pragma unroll
      for (int r = 0; r < 16; r++){
        float alr = __shfl(al, (r & 3) + 8 * (r >> 2) + 4 * hi);
        #pragma unroll
        for (int d2 = 0; d2 < 4; d2++) o[d2][r] *= alr;
      }
    }

    unsigned int u[2][4][2];
    #pragma unroll
    for (int kb = 0; kb < 2; kb++)
      #pragma unroll
      for (int t = 0; t < 4; t++)
        #pragma unroll
        for (int wd = 0; wd < 2; wd++)
          u[kb][t][wd] = (unsigned int)f2bf(sacc[kb][4 * t + 2 * wd])
                       | ((unsigned int)f2bf(sacc[kb][4 * t + 2 * wd + 1]) << 16);

    bf16x8 pa[4];
    #pragma unroll
    for (int ks = 0; ks < 4; ks++){
      const int kb = ks >> 1, s2 = ks & 1;
      unsigned int v0 = hi ? u[kb][2 * s2][0] : u[kb][2 * s2 + 1][0];
      unsigned int v1 = hi ? u[kb][2 * s2][1] : u[kb][2 * s2 + 1][1];
      unsigned int x0 = (unsigned int)__shfl_xor((int)v0, 32);
      unsigned int x1 = (unsigned int)__shfl_xor((int)v1, 32);
      union { bf16x8 v; unsigned int w[4]; } pw;
      pw.w[0] = hi ? x0 : u[kb][2 * s2][0];
      pw.w[1] = hi ? x1 : u[kb][2 * s2][1];
      pw.w[2] = hi ? u[kb][2 * s2 + 1][0] : x0;
      pw.w[3] = hi ? u[kb][2 * s2 + 1][1] : x1;
      pa[ks] = pw.v;
    }

    __builtin_amdgcn_s_setprio(1);
    #pragma unroll
    for (int d2 = 0; d2 < 4; d2++){
      #pragma unroll
      for (int ks = 0; ks < 4; ks++){
        bf16x8 vf = *(const bf16x8*)&VB[(d2 * 32 + l31) * 64 + ((ks * 16 + hi * 8) ^ ((l31 & 7) << 3))];
        o[d2] = __builtin_amdgcn_mfma_f32_32x32x16_bf16(pa[ks], vf, o[d2], 0, 0, 0);
      }
    }
    __builtin_amdgcn_s_setprio(0);
    __syncthreads();
    bf ^= 1;
  }

  float lrcp[16];
  #pragma unroll
  for (int r = 0; r < 16; r++)
    lrcp[r] = 1.0f / __shfl(l_, (r & 3) + 8 * (r >> 2) + 4 * hi);
  #pragma unroll
  for (int d2 = 0; d2 < 4; d2++)
    #pragma unroll
    for (int r = 0; r < 16; r++){
      size_t row = (size_t)b * S_ + qt * 32 + (r & 3) + 8 * (r >> 2) + 4 * hi;
      outb[row * D_ + h * HD_ + d2 * 32 + l31] = f2bf(o[d2][r] * lrcp[r]);
    }
  #undef STAGE_KV
}

extern "C" void kernel_launch(void* const* d_in, const int* in_sizes, int n_in,
                              void* d_out, int out_size, void* d_ws, size_t ws_size,
                              hipStream_t stream){
  const float* x  = (const float*)d_in[0];
  const float* Wq = (const float*)d_in[1];
  const float* bq = (const float*)d_in[2];
  const float* Wk = (const float*)d_in[3];
  const float* bk = (const float*)d_in[4];
  const float* Wv = (const float*)d_in[5];
  const float* bv = (const float*)d_in[6];
  const float* Wo = (const float*)d_in[7];
  const float* bo = (const float*)d_in[8];
  const float* qn = (const float*)d_in[9];
  const float* kn = (const float*)d_in[10];
  float* out = (float*)d_out;

  char* ws = (char*)d_ws;
  unsigned short* xb    = (unsigned short*)(ws + 0);          // 16,777,216 B
  unsigned short* wqkvT = (unsigned short*)(ws + 16777216);   // 12,582,912 B
  unsigned short* woT   = (unsigned short*)(ws + 29360128);   //  8,388,608 B
  unsigned short* qkv   = (unsigned short*)(ws + 37748736);   // 25,165,824 B
  unsigned short* attnO = (unsigned short*)(ws + 62914560);   // 16,777,216 B
  unsigned short* vt    = (unsigned short*)(ws + 79691776);   //  4,194,304 B

  prep<<<10752, 256, 0, stream>>>(x, Wq, Wk, Wv, Wo, xb, wqkvT, woT);
  gemm_bt<1><<<768, 256, 0, stream>>>(xb, wqkvT, bq, bk, bv, qn, kn, (void*)qkv, vt, 4096, 3072, 2048);
  attn<<<512, 256, 0, stream>>>(qkv, vt, attnO);
  gemm_bt<0><<<512, 256, 0, stream>>>(attnO, woT, bo, nullptr, nullptr, nullptr, nullptr, (void*)out, nullptr, 4096, 2048, 2048);
}

// Round 15
// 152.918 us; speedup vs baseline: 1.2715x; 1.2715x over previous
//
#include <hip/hip_runtime.h>
#include <hip/hip_bf16.h>

#define B_ 4
#define S_ 1024
#define D_ 2048
#define H_ 16
#define G_ 4
#define HD_ 128
#define NQKV_ 3072
#define SCALE_ 0.08838834764831845f
#define EPS_ 1e-6f

typedef __attribute__((ext_vector_type(8))) short bf16x8;
typedef __attribute__((ext_vector_type(4))) float f32x4;
typedef __attribute__((ext_vector_type(16))) float f32x16;

__device__ __forceinline__ float bf2f(unsigned short u){
  union { unsigned int i; float f; } v; v.i = ((unsigned int)u) << 16; return v.f;
}
__device__ __forceinline__ unsigned short f2bf(float f){
  union { float f; unsigned int i; } v; v.f = f;
  unsigned int x = v.i;
  return (unsigned short)((x + 0x7fffu + ((x >> 16) & 1u)) >> 16);
}
__device__ __forceinline__ void gld16(unsigned short* lds, const unsigned short* g){
  __builtin_amdgcn_global_load_lds(
      (const __attribute__((address_space(1))) unsigned int*)g,
      (__attribute__((address_space(3))) unsigned int*)lds, 16, 0, 0);
}

// ---------------- prep: x->bf16 (blocks 0..8191) + weight transposes ----------------
// Transpose writes packed: 2 bf16 per lane (full write coalescing).
__global__ void prep(const float* __restrict__ x, const float* __restrict__ Wq,
                     const float* __restrict__ Wk, const float* __restrict__ Wv,
                     const float* __restrict__ Wo, unsigned short* __restrict__ xb,
                     unsigned short* __restrict__ wqkvT, unsigned short* __restrict__ woT){
  __shared__ float tile[64][65];
  const int bid = blockIdx.x;
  if (bid < 8192){
    int i = bid * 256 + threadIdx.x;
    const float4 v = ((const float4*)x)[i];
    ushort4 o;
    o.x = f2bf(v.x); o.y = f2bf(v.y); o.z = f2bf(v.z); o.w = f2bf(v.w);
    ((ushort4*)xb)[i] = o;
    return;
  }
  const int wb = bid - 8192;
  const float* src; unsigned short* dst; int N, rowoff, t, nx;
  if (wb < 1024){ src = Wq; dst = wqkvT; N = 2048; rowoff = 0;    t = wb;        nx = 32; }
  else if (wb < 1280){ src = Wk; dst = wqkvT; N = 512; rowoff = 2048; t = wb - 1024; nx = 8; }
  else if (wb < 1536){ src = Wv; dst = wqkvT; N = 512; rowoff = 2560; t = wb - 1280; nx = 8; }
  else { src = Wo; dst = woT; N = 2048; rowoff = 0; t = wb - 1536; nx = 32; }
  const int n0 = (t % nx) * 64, k0 = (t / nx) * 64;
  const int c = threadIdx.x & 63, rb = threadIdx.x >> 6;
  #pragma unroll
  for (int j = 0; j < 16; j++){
    int r = rb + j * 4;
    tile[r][c] = src[(size_t)(k0 + r) * N + n0 + c];
  }
  __syncthreads();
  // packed write: lane -> row n0+r, k-cols k0+2c..2c+1 (uint = 2 bf16)
  const int c2 = threadIdx.x & 31, rb2 = threadIdx.x >> 5;
  #pragma unroll
  for (int j = 0; j < 8; j++){
    int r = rb2 + j * 8;
    unsigned int v = (unsigned int)f2bf(tile[2 * c2][r])
                   | ((unsigned int)f2bf(tile[2 * c2 + 1][r]) << 16);
    *(unsigned int*)&dst[(size_t)(n0 + r + rowoff) * 2048 + k0 + 2 * c2] = v;
  }
}

// ---------------- GEMM: C[M][N] = A[M][K] @ Bt[N][K]^T + bias ----------------
// 128x128 tile, BK=64, SINGLE-buffer LDS (32 KB -> 3 blocks/CU co-resident;
// m114 implicit cross-block overlap is the load-hiding mechanism — explicit
// dbuf costs a block and regresses, r14). XOR swizzle both-sides, XCD-chunked.
// MODE 1: Q/K tiles -> fused RMSNorm/RoPE -> qkv bf16; V tiles -> vt transpose.
// MODE 0: f32 out + bias.
template<int MODE>
__global__ __launch_bounds__(256, 2) void gemm_bt(const unsigned short* __restrict__ A,
    const unsigned short* __restrict__ Bt,
    const float* __restrict__ b0, const float* __restrict__ b1, const float* __restrict__ b2,
    const float* __restrict__ qn, const float* __restrict__ kn,
    void* __restrict__ Cout, unsigned short* __restrict__ vtOut, int M, int N, int K){
  const int tid = threadIdx.x, wid = tid >> 6, lane = tid & 63;
  const int l15 = lane & 15, l4 = lane >> 4;
  const int nwg = (N >> 7) * (M >> 7);
  const int chunk = nwg >> 3;
  const int ord = (blockIdx.x & 7) * chunk + (blockIdx.x >> 3);
  const int bn = (ord >> 5) * 128;           // M>>7 == 32
  const int bm = (ord & 31) * 128;
  const int wr = wid >> 1, wc = wid & 1;
  __shared__ __align__(16) unsigned short As[128 * 64];
  __shared__ __align__(16) unsigned short Bs[128 * 64];

  const int srow = lane >> 3;
  const int sofs = ((lane & 7) * 8) ^ (srow << 3);
  const unsigned short* pa = A  + (size_t)(bm + wid * 32 + srow) * K + sofs;
  const unsigned short* pb = Bt + (size_t)(bn + wid * 32 + srow) * K + sofs;
  unsigned short* la = As + wid * 32 * 64;
  unsigned short* lb = Bs + wid * 32 * 64;

  f32x4 acc[4][4];
  #pragma unroll
  for (int m2 = 0; m2 < 4; m2++)
    #pragma unroll
    for (int n2 = 0; n2 < 4; n2++) acc[m2][n2] = (f32x4){0.f, 0.f, 0.f, 0.f};

  const int rswz = (l15 & 7) << 3;
  for (int k0 = 0; k0 < K; k0 += 64){
    __syncthreads();
    #pragma unroll
    for (int i = 0; i < 4; i++){
      gld16(la + i * 8 * 64, pa + (size_t)(i * 8) * K + k0);
      gld16(lb + i * 8 * 64, pb + (size_t)(i * 8) * K + k0);
    }
    __syncthreads();
    bf16x8 af[4][2], bfv[4][2];
    #pragma unroll
    for (int m2 = 0; m2 < 4; m2++)
      #pragma unroll
      for (int ks = 0; ks < 2; ks++)
        af[m2][ks] = *(const bf16x8*)&As[(wr * 64 + m2 * 16 + l15) * 64 + ((ks * 32 + l4 * 8) ^ rswz)];
    #pragma unroll
    for (int n2 = 0; n2 < 4; n2++)
      #pragma unroll
      for (int ks = 0; ks < 2; ks++)
        bfv[n2][ks] = *(const bf16x8*)&Bs[(wc * 64 + n2 * 16 + l15) * 64 + ((ks * 32 + l4 * 8) ^ rswz)];
    #pragma unroll
    for (int ks = 0; ks < 2; ks++)
      #pragma unroll
      for (int m2 = 0; m2 < 4; m2++)
        #pragma unroll
        for (int n2 = 0; n2 < 4; n2++)
          acc[m2][n2] = __builtin_amdgcn_mfma_f32_16x16x32_bf16(af[m2][ks], bfv[n2][ks], acc[m2][n2], 0, 0, 0);
  }

  #pragma unroll
  for (int n2 = 0; n2 < 4; n2++){
    int col = bn + wc * 64 + n2 * 16 + l15;
    float bias;
    if (MODE == 1) bias = col < 2048 ? b0[col] : (col < 2560 ? b1[col - 2048] : b2[col - 2560]);
    else           bias = b0[col];
    #pragma unroll
    for (int m2 = 0; m2 < 4; m2++)
      #pragma unroll
      for (int r = 0; r < 4; r++) acc[m2][n2][r] += bias;
  }

  if (MODE == 1 && bn < 2560){
    __syncthreads();
    float* ssq = (float*)As;
    float part[4][4];
    #pragma unroll
    for (int m2 = 0; m2 < 4; m2++)
      #pragma unroll
      for (int r = 0; r < 4; r++){
        float p = 0.f;
        #pragma unroll
        for (int n2 = 0; n2 < 4; n2++) p += acc[m2][n2][r] * acc[m2][n2][r];
        #pragma unroll
        for (int off = 1; off < 16; off <<= 1) p += __shfl_xor(p, off);
        part[m2][r] = p;
      }
    if (l15 == 0){
      #pragma unroll
      for (int m2 = 0; m2 < 4; m2++)
        #pragma unroll
        for (int r = 0; r < 4; r++) ssq[wid * 64 + m2 * 16 + l4 * 4 + r] = part[m2][r];
    }
    __syncthreads();
    float rn[4][4];
    #pragma unroll
    for (int m2 = 0; m2 < 4; m2++)
      #pragma unroll
      for (int r = 0; r < 4; r++){
        int idx = m2 * 16 + l4 * 4 + r;
        float tot = ssq[wid * 64 + idx] + ssq[(wid ^ 1) * 64 + idx];
        rn[m2][r] = rsqrtf(tot * (1.0f / 128.0f) + EPS_);
      }
    const float* scv = (bn < 2048) ? qn : kn;
    const float sq = (bn < 2048) ? SCALE_ : 1.0f;   // fold SCALE into scl (rope is linear)
    float invf[4], scl[4];
    #pragma unroll
    for (int n2 = 0; n2 < 4; n2++){
      int ch = wc * 64 + n2 * 16 + l15;
      invf[n2] = exp2f((float)(ch >> 1) * -0.20762051f);
      scl[n2] = scv[ch] * sq;
    }
    const bool odd = (l15 & 1);
    unsigned short* outq = (unsigned short*)Cout;
    #pragma unroll
    for (int m2 = 0; m2 < 4; m2++)
      #pragma unroll
      for (int r = 0; r < 4; r++){
        int row = bm + wr * 64 + m2 * 16 + l4 * 4 + r;
        float sf = (float)(row & (S_ - 1));
        #pragma unroll
        for (int n2 = 0; n2 < 4; n2++){
          float v = acc[m2][n2][r] * rn[m2][r] * scl[n2];
          float vp = __shfl_xor(v, 1);
          float th = sf * invf[n2];
          float sn = __sinf(th), cs = __cosf(th);
          float outv = odd ? (vp * sn + v * cs) : (v * cs - vp * sn);
          int col = bn + wc * 64 + n2 * 16 + l15;
          outq[(size_t)row * N + col] = f2bf(outv);
        }
      }
  } else if (MODE == 1){
    // V tile -> vt transpose (2-pass LDS)
    const int b = bm >> 10;
    const int s0 = bm & 1023;
    const int g = (bn - 2560) >> 7;
    unsigned short* vtp = vtOut + (size_t)(b * G_ + g) * HD_ * (size_t)S_;
    unsigned short* tr = (unsigned short*)As;
    #pragma unroll
    for (int dh = 0; dh < 2; dh++){
      __syncthreads();
      if (wc == dh){
        #pragma unroll
        for (int n2 = 0; n2 < 4; n2++){
          int dp = n2 * 16 + l15;
          int cs = (dp & 7) << 3;
          #pragma unroll
          for (int m2 = 0; m2 < 4; m2++)
            #pragma unroll
            for (int r = 0; r < 4; r++){
              int s = wr * 64 + m2 * 16 + l4 * 4 + r;
              tr[dp * 128 + (s ^ cs)] = f2bf(acc[m2][n2][r]);
            }
        }
      }
      __syncthreads();
      int dp = tid >> 2;
      int sb = (tid & 3) * 32;
      int cs = (dp & 7) << 3;
      #pragma unroll
      for (int jj = 0; jj < 4; jj++){
        bf16x8 vv = *(const bf16x8*)&tr[dp * 128 + ((sb + jj * 8) ^ cs)];
        *(bf16x8*)&vtp[(size_t)(dh * 64 + dp) * S_ + s0 + sb + jj * 8] = vv;
      }
    }
  } else {
    #pragma unroll
    for (int m2 = 0; m2 < 4; m2++)
      #pragma unroll
      for (int n2 = 0; n2 < 4; n2++){
        int col = bn + wc * 64 + n2 * 16 + l15;
        #pragma unroll
        for (int r = 0; r < 4; r++){
          int row = bm + wr * 64 + m2 * 16 + l4 * 4 + r;
          ((float*)Cout)[(size_t)row * N + col] = acc[m2][n2][r];
        }
      }
  }
}

// ---------------- flash attention: 32x32 MFMA, swapped QK^T, in-reg softmax ----
__global__ __launch_bounds__(256, 2) void attn(const unsigned short* __restrict__ qkv,
    const unsigned short* __restrict__ vt, unsigned short* __restrict__ outb){
  const int bid = blockIdx.x;
  const int xcd = bid & 7, idx = bid >> 3;
  const int gb = xcd * 2 + (idx & 1);
  const int qh = idx >> 1;
  const int qt = (qh < 16) ? (31 - qh) : (qh - 16);   // CU pair (qt, 31-qt): even work
  const int g = gb & 3, b = gb >> 2;
  const int tid = threadIdx.x, w = tid >> 6, lane = tid & 63;
  const int h = g * 4 + w;
  const int l31 = lane & 31, hi = lane >> 5;
  const int nkt = qt / 2 + 1;
  __shared__ __align__(16) unsigned short Ks[2][64 * 128];  // swz: col ^= (row&15)<<3
  __shared__ __align__(16) unsigned short Vs[2][128 * 64];  // swz: col ^= (row&7)<<3

  #define STAGE_KV(BF, KT)                                                              \
    do {                                                                                \
      _Pragma("unroll")                                                                 \
      for (int i_ = 0; i_ < 4; i_++){                                                   \
        int row_ = w * 16 + i_ * 4 + (lane >> 4);                                       \
        const unsigned short* src_ = qkv + (size_t)(b * S_ + (KT) * 64 + row_) * NQKV_  \
            + 2048 + g * HD_ + (((lane & 15) * 8) ^ ((row_ & 15) << 3));                \
        gld16(&Ks[BF][(w * 16 + i_ * 4) * 128], src_);                                  \
      }                                                                                 \
      _Pragma("unroll")                                                                 \
      for (int i_ = 0; i_ < 4; i_++){                                                   \
        int row_ = w * 32 + i_ * 8 + (lane >> 3);                                       \
        const unsigned short* src_ = vt + (size_t)((b * G_ + g) * HD_ + row_) * S_      \
            + (KT) * 64 + (((lane & 7) * 8) ^ ((row_ & 7) << 3));                       \
        gld16(&Vs[BF][(w * 32 + i_ * 8) * 64], src_);                                   \
      }                                                                                 \
    } while (0)

  bf16x8 qf[8];
  {
    const unsigned short* qp = qkv + ((size_t)b * S_ + qt * 32 + l31) * NQKV_ + h * HD_ + hi * 8;
    #pragma unroll
    for (int ks = 0; ks < 8; ks++) qf[ks] = *(const bf16x8*)&qp[ks * 16];
  }
  f32x16 o[4];
  #pragma unroll
  for (int d2 = 0; d2 < 4; d2++)
    #pragma unroll
    for (int r = 0; r < 16; r++) o[d2][r] = 0.f;
  float m_ = -1e30f, l_ = 0.f;

  int bf = 0;
  STAGE_KV(0, 0);
  __syncthreads();

  for (int kt = 0; kt < nkt; ++kt){
    if (kt + 1 < nkt){
      if (bf) STAGE_KV(0, kt + 1); else STAGE_KV(1, kt + 1);
    }
    const unsigned short* KB = Ks[bf];
    const unsigned short* VB = Vs[bf];
    const bool diag = (kt == nkt - 1);

    f32x16 sacc[2];
    #pragma unroll
    for (int kb = 0; kb < 2; kb++){
      f32x16 acc;
      #pragma unroll
      for (int r = 0; r < 16; r++) acc[r] = 0.f;
      __builtin_amdgcn_s_setprio(1);
      #pragma unroll
      for (int ks = 0; ks < 8; ks++){
        bf16x8 kf = *(const bf16x8*)&KB[(kb * 32 + l31) * 128 + ((ks * 16 + hi * 8) ^ ((l31 & 15) << 3))];
        acc = __builtin_amdgcn_mfma_f32_32x32x16_bf16(kf, qf[ks], acc, 0, 0, 0);
      }
      __builtin_amdgcn_s_setprio(0);
      sacc[kb] = acc;
    }

    if (diag){
      const int qrow = qt * 32 + l31;
      #pragma unroll
      for (int kb = 0; kb < 2; kb++)
        #pragma unroll
        for (int r = 0; r < 16; r++){
          int key = kt * 64 + kb * 32 + (r & 3) + 8 * (r >> 2) + 4 * hi;
          float v = sacc[kb][r] * SCALE_;
          sacc[kb][r] = (key > qrow) ? -1e30f : v;
        }
    } else {
      #pragma unroll
      for (int kb = 0; kb < 2; kb++)
        #pragma unroll
        for (int r = 0; r < 16; r++) sacc[kb][r] *= SCALE_;
    }

    float tm = sacc[0][0];
    #pragma unroll
    for (int r = 1; r < 16; r++) tm = fmaxf(tm, sacc[0][r]);
    #pragma unroll
    for (int r = 0; r < 16; r++) tm = fmaxf(tm, sacc[1][r]);
    tm = fmaxf(tm, __shfl_xor(tm, 32));

    float al = 1.0f;
    bool rescale = false;
    if (!__all(tm <= m_ + 8.0f)){
      float mn = fmaxf(m_, tm);
      al = __expf(m_ - mn);
      m_ = mn;
      rescale = true;
    }

    float rs = 0.f;
    #pragma unroll
    for (int kb = 0; kb < 2; kb++)
      #pragma unroll
      for (int r = 0; r < 16; r++){
        float p = __expf(sacc[kb][r] - m_);
        sacc[kb][r] = p;
        rs += p;
      }
    rs += __shfl_xor(rs, 32);
    l_ = l_ * al + rs;

    if (rescale){
      #pragma unroll
      for (int r = 0; r < 16; r++){
        float alr = __shfl(al, (r & 3) + 8 * (r >> 2) + 4 * hi);
        #pragma unroll
        for (int d2 = 0; d2 < 4; d2++) o[d2][r] *= alr;
      }
    }

    unsigned int u[2][4][2];
    #pragma unroll
    for (int kb = 0; kb < 2; kb++)
      #pragma unroll
      for (int t = 0; t < 4; t++)
        #pragma unroll
        for (int wd = 0; wd < 2; wd++)
          u[kb][t][wd] = (unsigned int)f2bf(sacc[kb][4 * t + 2 * wd])
                       | ((unsigned int)f2bf(sacc[kb][4 * t + 2 * wd + 1]) << 16);

    bf16x8 pa[4];
    #pragma unroll
    for (int ks = 0; ks < 4; ks++){
      const int kb = ks >> 1, s2 = ks & 1;
      unsigned int v0 = hi ? u[kb][2 * s2][0] : u[kb][2 * s2 + 1][0];
      unsigned int v1 = hi ? u[kb][2 * s2][1] : u[kb][2 * s2 + 1][1];
      unsigned int x0 = (unsigned int)__shfl_xor((int)v0, 32);
      unsigned int x1 = (unsigned int)__shfl_xor((int)v1, 32);
      union { bf16x8 v; unsigned int w[4]; } pw;
      pw.w[0] = hi ? x0 : u[kb][2 * s2][0];
      pw.w[1] = hi ? x1 : u[kb][2 * s2][1];
      pw.w[2] = hi ? u[kb][2 * s2 + 1][0] : x0;
      pw.w[3] = hi ? u[kb][2 * s2 + 1][1] : x1;
      pa[ks] = pw.v;
    }

    __builtin_amdgcn_s_setprio(1);
    #pragma unroll
    for (int d2 = 0; d2 < 4; d2++){
      #pragma unroll
      for (int ks = 0; ks < 4; ks++){
        bf16x8 vf = *(const bf16x8*)&VB[(d2 * 32 + l31) * 64 + ((ks * 16 + hi * 8) ^ ((l31 & 7) << 3))];
        o[d2] = __builtin_amdgcn_mfma_f32_32x32x16_bf16(pa[ks], vf, o[d2], 0, 0, 0);
      }
    }
    __builtin_amdgcn_s_setprio(0);
    __syncthreads();
    bf ^= 1;
  }

  float lrcp[16];
  #pragma unroll
  for (int r = 0; r < 16; r++)
    lrcp[r] = 1.0f / __shfl(l_, (r & 3) + 8 * (r >> 2) + 4 * hi);
  #pragma unroll
  for (int d2 = 0; d2 < 4; d2++)
    #pragma unroll
    for (int r = 0; r < 16; r++){
      size_t row = (size_t)b * S_ + qt * 32 + (r & 3) + 8 * (r >> 2) + 4 * hi;
      outb[row * D_ + h * HD_ + d2 * 32 + l31] = f2bf(o[d2][r] * lrcp[r]);
    }
  #undef STAGE_KV
}

extern "C" void kernel_launch(void* const* d_in, const int* in_sizes, int n_in,
                              void* d_out, int out_size, void* d_ws, size_t ws_size,
                              hipStream_t stream){
  const float* x  = (const float*)d_in[0];
  const float* Wq = (const float*)d_in[1];
  const float* bq = (const float*)d_in[2];
  const float* Wk = (const float*)d_in[3];
  const float* bk = (const float*)d_in[4];
  const float* Wv = (const float*)d_in[5];
  const float* bv = (const float*)d_in[6];
  const float* Wo = (const float*)d_in[7];
  const float* bo = (const float*)d_in[8];
  const float* qn = (const float*)d_in[9];
  const float* kn = (const float*)d_in[10];
  float* out = (float*)d_out;

  char* ws = (char*)d_ws;
  unsigned short* xb    = (unsigned short*)(ws + 0);          // 16,777,216 B
  unsigned short* wqkvT = (unsigned short*)(ws + 16777216);   // 12,582,912 B
  unsigned short* woT   = (unsigned short*)(ws + 29360128);   //  8,388,608 B
  unsigned short* qkv   = (unsigned short*)(ws + 37748736);   // 25,165,824 B
  unsigned short* attnO = (unsigned short*)(ws + 62914560);   // 16,777,216 B
  unsigned short* vt    = (unsigned short*)(ws + 79691776);   //  4,194,304 B

  prep<<<10752, 256, 0, stream>>>(x, Wq, Wk, Wv, Wo, xb, wqkvT, woT);
  gemm_bt<1><<<768, 256, 0, stream>>>(xb, wqkvT, bq, bk, bv, qn, kn, (void*)qkv, vt, 4096, 3072, 2048);
  attn<<<512, 256, 0, stream>>>(qkv, vt, attnO);
  gemm_bt<0><<<512, 256, 0, stream>>>(attnO, woT, bo, nullptr, nullptr, nullptr, nullptr, (void*)out, nullptr, 4096, 2048, 2048);
}